// Round 7
// baseline (227.323 us; speedup 1.0000x reference)
//
#include <hip/hip_runtime.h>

// SSIM, wave-per-row-strip, software-pipelined, phase-split, DPP halo,
// LDS history ring.
// R10: evidence across R4-R9: time invariant to wave count (R6), vector-mem
// instruction count (R7: removed loads were L1-hit zrow reads), LDS-pipe
// traffic (R9) -> binder is the per-CU L1-MISS path (~1 line/10cy service).
// Steady step = 128 miss-lines/wave, HALF of them the old-row re-reads
// (ox/oy), which cannot hit L2 (per-XCD live set 11MB > 4MB). Fix: keep the
// 11-row raw x,y history in a per-wave LDS ring (11 slots x 2 streams x 2KB
// = 44KB/wave, 2-wave blocks = 88KB <= 160KB/CU). Old rows now come from
// LDS (pipe freed by R9's DPP halo); global old-row loads deleted -> total
// miss lines ~5.4M -> ~3.4M. Same values subtracted -> bit-identical result.
// No barriers: ring is wave-private; DS pipe is in-order per wave, so
// read-slot-before-overwrite-slot within a body is safe.

static constexpr int HI = 512, WI = 512;
static constexpr int RS = 16;             // output rows per wave-strip
static constexpr int SPB = HI / RS;       // strips per batch = 32
static constexpr int RINGB = 11 * 2 * (WI * 4);  // 45056 B per wave

struct R8 { float4 a, b; };

__device__ __forceinline__ R8 ld8(const float* p) {
  R8 r; r.a = ((const float4*)p)[0]; r.b = ((const float4*)p)[1]; return r;
}

__device__ __forceinline__ void unp(const R8& v, float o[8]) {
  o[0]=v.a.x; o[1]=v.a.y; o[2]=v.a.z; o[3]=v.a.w;
  o[4]=v.b.x; o[5]=v.b.y; o[6]=v.b.z; o[7]=v.b.w;
}

// value from lane-1 across whole wave; lane 0 -> 0   (v_mov_dpp wave_shr:1)
__device__ __forceinline__ float shr1(float x) {
  return __int_as_float(__builtin_amdgcn_update_dpp(
      0, __float_as_int(x), 0x138, 0xf, 0xf, true));
}
// value from lane+1 across whole wave; lane 63 -> 0  (v_mov_dpp wave_shl:1)
__device__ __forceinline__ float shl1(float x) {
  return __int_as_float(__builtin_amdgcn_update_dpp(
      0, __float_as_int(x), 0x130, 0xf, 0xf, true));
}

__device__ __forceinline__ void horiz11(const float v[8], float H[8]) {
  float L[5], R[5];
#pragma unroll
  for (int k = 0; k < 5; ++k) {
    L[k] = shr1(v[3 + k]);   // image cols -5..-1 zero-pad (lane0 bound_ctrl)
    R[k] = shl1(v[k]);       // image cols 512..516 zero-pad (lane63)
  }
  float h = (((L[0] + L[1]) + (L[2] + L[3])) + ((L[4] + v[0]) + (v[1] + v[2])))
            + ((v[3] + v[4]) + v[5]);
  H[0] = h;
  h = h - L[0] + v[6]; H[1] = h;
  h = h - L[1] + v[7]; H[2] = h;
  h = h - L[2] + R[0]; H[3] = h;
  h = h - L[3] + R[1]; H[4] = h;
  h = h - L[4] + R[2]; H[5] = h;
  h = h - v[0] + R[3]; H[6] = h;
  h = h - v[1] + R[4]; H[7] = h;
}

__global__ __launch_bounds__(128)
void ssim_wave(const float* __restrict__ img, const float* __restrict__ ref,
               const float* __restrict__ drng, const float* __restrict__ zrow,
               float* __restrict__ out)
{
  extern __shared__ char lds_raw[];

  // Bijective XCD swizzle (1024 blocks % 8 == 0): adjacent strips share 10
  // halo rows -> keep them on the same per-XCD L2.
  int bid = (int)blockIdx.x;
  const int nb = (int)gridDim.x;
  if ((nb & 7) == 0) {
    const int cpx = nb >> 3;
    bid = (bid & 7) * cpx + (bid >> 3);
  }

  const int lane  = threadIdx.x & 63;
  const int wslot = threadIdx.x >> 6;       // 0..1
  const int wv    = bid * 2 + wslot;
  const int b     = wv / SPB;
  const int r0    = (wv % SPB) * RS;
  const int c0    = lane * 8;

  // per-wave LDS ring: slot*4096 + stream*2048 + lane*32 bytes
  float4* ring = (float4*)(lds_raw + wslot * RINGB);
  auto ringw = [&](int slot, const R8& vx, const R8& vy) {
    float4* p = ring + slot * 256 + lane * 2;
    p[0] = vx.a; p[1] = vx.b;
    p[128] = vy.a; p[129] = vy.b;
  };
  auto ringr = [&](int slot, R8& vx, R8& vy) {
    float4* p = ring + slot * 256 + lane * 2;
    vx.a = p[0]; vx.b = p[1];
    vy.a = p[128]; vy.b = p[129];
  };

  const float dr  = drng[b];
  const float C1  = (0.01f * dr) * (0.01f * dr);
  const float C2  = (0.03f * dr) * (0.03f * dr);
  const float inv_n    = 1.0f / 121.0f;
  const float cov_norm = 121.0f / 120.0f;

  const size_t base = (size_t)b * ((size_t)HI * WI);
  const float* xb = img + base;
  const float* yb = ref + base;
  float*       ob = out + base;

  // wave-uniform pointer select; OOB -> dummy zero row (branch-free loads)
  auto nrow = [&](const float* tb, int t) -> const float* {
    const int r = r0 - 5 + t;
    return (((unsigned)r < (unsigned)HI) ? tb + (size_t)r * WI : zrow) + c0;
  };

  float Sx[8], Sy[8], Sxx[8], Syy[8], Sxy[8];
#pragma unroll
  for (int c = 0; c < 8; ++c) { Sx[c]=0.f; Sy[c]=0.f; Sxx[c]=0.f; Syy[c]=0.f; Sxy[c]=0.f; }

  auto accA = [&](const float xn[8], const float yn[8]) {
#pragma unroll
    for (int c = 0; c < 8; ++c) {
      Sx[c] += xn[c];  Sy[c] += yn[c];
      Sxx[c] = fmaf(xn[c], xn[c], Sxx[c]);
      Syy[c] = fmaf(yn[c], yn[c], Syy[c]);
      Sxy[c] = fmaf(xn[c], yn[c], Sxy[c]);
    }
  };
  auto accB = [&](const float xn[8], const float yn[8],
                  const float xo[8], const float yo[8]) {
#pragma unroll
    for (int c = 0; c < 8; ++c) {
      Sx[c] += xn[c] - xo[c];
      Sy[c] += yn[c] - yo[c];
      Sxx[c] = fmaf(xn[c], xn[c], fmaf(-xo[c], xo[c], Sxx[c]));
      Syy[c] = fmaf(yn[c], yn[c], fmaf(-yo[c], yo[c], Syy[c]));
      Sxy[c] = fmaf(xn[c], yn[c], fmaf(-xo[c], yo[c], Sxy[c]));
    }
  };

  auto emit = [&](int t) {   // output row r0 + t - 10
    float H0[8], H1[8], H2[8], H3[8], H4[8];
    horiz11(Sx,  H0);
    horiz11(Sy,  H1);
    horiz11(Sxx, H2);
    horiz11(Syy, H3);
    horiz11(Sxy, H4);
    float res[8];
#pragma unroll
    for (int c = 0; c < 8; ++c) {
      const float ux  = H0[c] * inv_n, uy  = H1[c] * inv_n;
      const float uxx = H2[c] * inv_n, uyy = H3[c] * inv_n, uxy = H4[c] * inv_n;
      const float vx  = cov_norm * (uxx - ux * ux);
      const float vy  = cov_norm * (uyy - uy * uy);
      const float vxy = cov_norm * (uxy - ux * uy);
      const float A1 = 2.f * ux * uy + C1;
      const float A2 = 2.f * vxy + C2;
      const float B1 = ux * ux + uy * uy + C1;
      const float B2 = vx + vy + C2;
      res[c] = (A1 * A2) * __builtin_amdgcn_rcpf(B1 * B2);
    }
    const int ro = r0 + t - 10;
    float4* po = (float4*)(ob + (size_t)ro * WI + c0);
    po[0] = make_float4(res[0], res[1], res[2], res[3]);
    po[1] = make_float4(res[4], res[5], res[6], res[7]);
  };

  // depth-2 pipeline slots for the NEW streams only
  R8 nx[2], ny[2];
  nx[0] = ld8(nrow(xb, 0)); ny[0] = ld8(nrow(yb, 0));
  nx[1] = ld8(nrow(xb, 1)); ny[1] = ld8(nrow(yb, 1));

  // ---- Phase A: t = 0..10 — add-only; stash each row into the ring ----
#pragma unroll 2
  for (int t = 0; t < 11; ++t) {
    const int s = t & 1;
    float xn[8], yn[8];
    unp(nx[s], xn); unp(ny[s], yn);
    ringw(t, nx[s], ny[s]);               // slot t (t < 11)
    if (t + 2 < 26) { nx[s] = ld8(nrow(xb, t + 2)); ny[s] = ld8(nrow(yb, t + 2)); }
    accA(xn, yn);
    if (t == 10) emit(10);
  }

  // ---- Phase B: t = 11..25 — slide via ring read, then overwrite slot ----
  auto stepB = [&](int t, int s, bool issue) {
    const int slot = (t >= 22) ? (t - 22) : (t - 11);   // t % 11
    R8 oxr, oyr;
    ringr(slot, oxr, oyr);                // read old rows (in-order DS pipe:
    ringw(slot, nx[s], ny[s]);            //  safe to overwrite same slot after)
    float xn[8], yn[8], xo[8], yo[8];
    unp(nx[s], xn); unp(ny[s], yn); unp(oxr, xo); unp(oyr, yo);
    if (issue) { nx[s] = ld8(nrow(xb, t + 2)); ny[s] = ld8(nrow(yb, t + 2)); }
    accB(xn, yn, xo, yo);
    emit(t);
  };

#pragma unroll 1
  for (int u = 0; u < 6; ++u) {          // t = 11..22, slot parity (1,0)
    stepB(11 + 2 * u, 1, true);
    stepB(12 + 2 * u, 0, true);
  }
  stepB(23, 1, true);                    // issues t=25
  stepB(24, 0, false);
  stepB(25, 1, false);
}

extern "C" void kernel_launch(void* const* d_in, const int* in_sizes, int n_in,
                              void* d_out, int out_size, void* d_ws, size_t ws_size,
                              hipStream_t stream)
{
  const float* img = (const float*)d_in[0];
  const float* ref = (const float*)d_in[1];
  const float* drg = (const float*)d_in[2];
  float* out = (float*)d_out;

  static bool attr_done = false;
  if (!attr_done) {   // allow >64KB dynamic LDS (gfx950 workgroup max 160KB)
    (void)hipFuncSetAttribute((const void*)ssim_wave,
                              hipFuncAttributeMaxDynamicSharedMemorySize,
                              2 * RINGB);
    attr_done = true;
  }

  // zero dummy row (d_ws is re-poisoned to 0xAA before every launch)
  (void)hipMemsetAsync(d_ws, 0, (size_t)WI * sizeof(float) + 64, stream);

  const int B = in_sizes[0] / (HI * WI);          // 64
  const int waves = B * SPB;                      // 2048
  dim3 grid(waves / 2);                           // 1024 blocks, 2 waves each
  dim3 block(128);
  hipLaunchKernelGGL(ssim_wave, grid, block, 2 * RINGB, stream,
                     img, ref, drg, (const float*)d_ws, out);
}

// Round 8
// 214.264 us; speedup vs baseline: 1.0609x; 1.0609x over previous
//
#include <hip/hip_runtime.h>

// SSIM, wave-per-row-strip, software-pipelined, phase-split, DPP halo,
// LDS history ring (conflict-free layout, 1-wave blocks).
// R11: R10 proved the ring concept (FETCH 178->101 MB, old-row global loads
// gone) but regressed on two implementation faults: (1) ring stride 32B/lane
// -> ds_*_b128 16-way bank conflicts (SQ_LDS_BANK_CONFLICT 12.7M cycles);
// (2) 90KB 2-wave blocks -> 1 block/CU = 1.7 waves/CU resident (occupancy
// 5.4%), nothing to hide the remaining global-load latency.
// Fixes: ring slot stored as four contiguous 1KB sub-blocks (xa|xb|ya|yb),
// each lane reading/writing lane*16B contiguous = the conflict-free b128
// pattern; blocks are a single wave (64 thr) with 44KB dynamic LDS -> LDS
// caps at 3 blocks/CU = 3 waves/CU (1.75x R10 residency). Slot schedule,
// DPP halo, phase split, depth-2 pipeline unchanged from the passing R10.

static constexpr int HI = 512, WI = 512;
static constexpr int RS = 16;             // output rows per wave-strip
static constexpr int SPB = HI / RS;       // strips per batch = 32
static constexpr int RINGB = 11 * 4 * 1024;  // 11 slots x 4KB = 45056 B

struct R8 { float4 a, b; };

__device__ __forceinline__ R8 ld8(const float* p) {
  R8 r; r.a = ((const float4*)p)[0]; r.b = ((const float4*)p)[1]; return r;
}

__device__ __forceinline__ void unp(const R8& v, float o[8]) {
  o[0]=v.a.x; o[1]=v.a.y; o[2]=v.a.z; o[3]=v.a.w;
  o[4]=v.b.x; o[5]=v.b.y; o[6]=v.b.z; o[7]=v.b.w;
}

// value from lane-1 across whole wave; lane 0 -> 0   (v_mov_dpp wave_shr:1)
__device__ __forceinline__ float shr1(float x) {
  return __int_as_float(__builtin_amdgcn_update_dpp(
      0, __float_as_int(x), 0x138, 0xf, 0xf, true));
}
// value from lane+1 across whole wave; lane 63 -> 0  (v_mov_dpp wave_shl:1)
__device__ __forceinline__ float shl1(float x) {
  return __int_as_float(__builtin_amdgcn_update_dpp(
      0, __float_as_int(x), 0x130, 0xf, 0xf, true));
}

__device__ __forceinline__ void horiz11(const float v[8], float H[8]) {
  float L[5], R[5];
#pragma unroll
  for (int k = 0; k < 5; ++k) {
    L[k] = shr1(v[3 + k]);   // image cols -5..-1 zero-pad (lane0 bound_ctrl)
    R[k] = shl1(v[k]);       // image cols 512..516 zero-pad (lane63)
  }
  float h = (((L[0] + L[1]) + (L[2] + L[3])) + ((L[4] + v[0]) + (v[1] + v[2])))
            + ((v[3] + v[4]) + v[5]);
  H[0] = h;
  h = h - L[0] + v[6]; H[1] = h;
  h = h - L[1] + v[7]; H[2] = h;
  h = h - L[2] + R[0]; H[3] = h;
  h = h - L[3] + R[1]; H[4] = h;
  h = h - L[4] + R[2]; H[5] = h;
  h = h - v[0] + R[3]; H[6] = h;
  h = h - v[1] + R[4]; H[7] = h;
}

__global__ __launch_bounds__(64)
void ssim_wave(const float* __restrict__ img, const float* __restrict__ ref,
               const float* __restrict__ drng, const float* __restrict__ zrow,
               float* __restrict__ out)
{
  extern __shared__ char lds_raw[];

  // Bijective XCD swizzle (2048 blocks % 8 == 0): adjacent strips share 10
  // halo rows -> keep them on the same per-XCD L2.
  int bid = (int)blockIdx.x;
  const int nb = (int)gridDim.x;
  if ((nb & 7) == 0) {
    const int cpx = nb >> 3;
    bid = (bid & 7) * cpx + (bid >> 3);
  }

  const int lane = threadIdx.x & 63;
  const int wv   = bid;                    // one wave per block
  const int b    = wv / SPB;
  const int r0   = (wv % SPB) * RS;
  const int c0   = lane * 8;

  // ring slot s at byte s*4096: [xa 1KB | xb 1KB | ya 1KB | yb 1KB],
  // each sub-block accessed lane*16B contiguous -> conflict-free b128.
  auto ringw = [&](int slot, const R8& vx, const R8& vy) {
    float4* p = (float4*)(lds_raw + slot * 4096);
    p[lane]       = vx.a;
    p[64 + lane]  = vx.b;
    p[128 + lane] = vy.a;
    p[192 + lane] = vy.b;
  };
  auto ringr = [&](int slot, R8& vx, R8& vy) {
    const float4* p = (const float4*)(lds_raw + slot * 4096);
    vx.a = p[lane];
    vx.b = p[64 + lane];
    vy.a = p[128 + lane];
    vy.b = p[192 + lane];
  };

  const float dr  = drng[b];
  const float C1  = (0.01f * dr) * (0.01f * dr);
  const float C2  = (0.03f * dr) * (0.03f * dr);
  const float inv_n    = 1.0f / 121.0f;
  const float cov_norm = 121.0f / 120.0f;

  const size_t base = (size_t)b * ((size_t)HI * WI);
  const float* xb = img + base;
  const float* yb = ref + base;
  float*       ob = out + base;

  // wave-uniform pointer select; OOB -> dummy zero row (branch-free loads)
  auto nrow = [&](const float* tb, int t) -> const float* {
    const int r = r0 - 5 + t;
    return (((unsigned)r < (unsigned)HI) ? tb + (size_t)r * WI : zrow) + c0;
  };

  float Sx[8], Sy[8], Sxx[8], Syy[8], Sxy[8];
#pragma unroll
  for (int c = 0; c < 8; ++c) { Sx[c]=0.f; Sy[c]=0.f; Sxx[c]=0.f; Syy[c]=0.f; Sxy[c]=0.f; }

  auto accA = [&](const float xn[8], const float yn[8]) {
#pragma unroll
    for (int c = 0; c < 8; ++c) {
      Sx[c] += xn[c];  Sy[c] += yn[c];
      Sxx[c] = fmaf(xn[c], xn[c], Sxx[c]);
      Syy[c] = fmaf(yn[c], yn[c], Syy[c]);
      Sxy[c] = fmaf(xn[c], yn[c], Sxy[c]);
    }
  };
  auto accB = [&](const float xn[8], const float yn[8],
                  const float xo[8], const float yo[8]) {
#pragma unroll
    for (int c = 0; c < 8; ++c) {
      Sx[c] += xn[c] - xo[c];
      Sy[c] += yn[c] - yo[c];
      Sxx[c] = fmaf(xn[c], xn[c], fmaf(-xo[c], xo[c], Sxx[c]));
      Syy[c] = fmaf(yn[c], yn[c], fmaf(-yo[c], yo[c], Syy[c]));
      Sxy[c] = fmaf(xn[c], yn[c], fmaf(-xo[c], yo[c], Sxy[c]));
    }
  };

  auto emit = [&](int t) {   // output row r0 + t - 10
    float H0[8], H1[8], H2[8], H3[8], H4[8];
    horiz11(Sx,  H0);
    horiz11(Sy,  H1);
    horiz11(Sxx, H2);
    horiz11(Syy, H3);
    horiz11(Sxy, H4);
    float res[8];
#pragma unroll
    for (int c = 0; c < 8; ++c) {
      const float ux  = H0[c] * inv_n, uy  = H1[c] * inv_n;
      const float uxx = H2[c] * inv_n, uyy = H3[c] * inv_n, uxy = H4[c] * inv_n;
      const float vx  = cov_norm * (uxx - ux * ux);
      const float vy  = cov_norm * (uyy - uy * uy);
      const float vxy = cov_norm * (uxy - ux * uy);
      const float A1 = 2.f * ux * uy + C1;
      const float A2 = 2.f * vxy + C2;
      const float B1 = ux * ux + uy * uy + C1;
      const float B2 = vx + vy + C2;
      res[c] = (A1 * A2) * __builtin_amdgcn_rcpf(B1 * B2);
    }
    const int ro = r0 + t - 10;
    float4* po = (float4*)(ob + (size_t)ro * WI + c0);
    po[0] = make_float4(res[0], res[1], res[2], res[3]);
    po[1] = make_float4(res[4], res[5], res[6], res[7]);
  };

  // depth-2 pipeline slots for the NEW streams only
  R8 nx[2], ny[2];
  nx[0] = ld8(nrow(xb, 0)); ny[0] = ld8(nrow(yb, 0));
  nx[1] = ld8(nrow(xb, 1)); ny[1] = ld8(nrow(yb, 1));

  // ---- Phase A: t = 0..10 — add-only; stash each row into the ring ----
#pragma unroll 2
  for (int t = 0; t < 11; ++t) {
    const int s = t & 1;
    float xn[8], yn[8];
    unp(nx[s], xn); unp(ny[s], yn);
    ringw(t, nx[s], ny[s]);               // slot t (t < 11)
    if (t + 2 < 26) { nx[s] = ld8(nrow(xb, t + 2)); ny[s] = ld8(nrow(yb, t + 2)); }
    accA(xn, yn);
    if (t == 10) emit(10);
  }

  // ---- Phase B: t = 11..25 — slide via ring read, then overwrite slot ----
  auto stepB = [&](int t, int s, bool issue) {
    const int slot = (t >= 22) ? (t - 22) : (t - 11);   // t % 11
    R8 oxr, oyr;
    ringr(slot, oxr, oyr);                // read old rows (in-order DS pipe:
    ringw(slot, nx[s], ny[s]);            //  safe to overwrite same slot after)
    float xn[8], yn[8], xo[8], yo[8];
    unp(nx[s], xn); unp(ny[s], yn); unp(oxr, xo); unp(oyr, yo);
    if (issue) { nx[s] = ld8(nrow(xb, t + 2)); ny[s] = ld8(nrow(yb, t + 2)); }
    accB(xn, yn, xo, yo);
    emit(t);
  };

#pragma unroll 1
  for (int u = 0; u < 6; ++u) {          // t = 11..22, slot parity (1,0)
    stepB(11 + 2 * u, 1, true);
    stepB(12 + 2 * u, 0, true);
  }
  stepB(23, 1, true);                    // issues t=25
  stepB(24, 0, false);
  stepB(25, 1, false);
}

extern "C" void kernel_launch(void* const* d_in, const int* in_sizes, int n_in,
                              void* d_out, int out_size, void* d_ws, size_t ws_size,
                              hipStream_t stream)
{
  const float* img = (const float*)d_in[0];
  const float* ref = (const float*)d_in[1];
  const float* drg = (const float*)d_in[2];
  float* out = (float*)d_out;

  // zero dummy row (d_ws is re-poisoned to 0xAA before every launch)
  (void)hipMemsetAsync(d_ws, 0, (size_t)WI * sizeof(float) + 64, stream);

  const int B = in_sizes[0] / (HI * WI);          // 64
  const int waves = B * SPB;                      // 2048
  dim3 grid(waves);                               // 2048 blocks, 1 wave each
  dim3 block(64);
  hipLaunchKernelGGL(ssim_wave, grid, block, RINGB, stream,
                     img, ref, drg, (const float*)d_ws, out);
}